// Round 12
// baseline (378.558 us; speedup 1.0000x reference)
//
#include <hip/hip_runtime.h>
#include <stdint.h>

// Problem constants
#define LSEQ 2048
#define EMB  1024
#define NH   16
#define HWID 64
#define SCALEF 0.125f   // 1/sqrt(64), folded into Q during rearrange

typedef __attribute__((ext_vector_type(4))) float  f32x4;
typedef __attribute__((ext_vector_type(8))) short  bf16x8;   // 8 bf16 in 4 VGPRs (MFMA operand)
typedef __attribute__((ext_vector_type(8))) unsigned short u16x8;
typedef __attribute__((ext_vector_type(4))) unsigned short u16x4;

static __device__ __forceinline__ unsigned short f2bf(float f) {
    union { float f; unsigned int u; } v; v.f = f;
    unsigned int r = (v.u + 0x7FFFu + ((v.u >> 16) & 1u)) >> 16;  // RNE
    return (unsigned short)r;
}
static __device__ __forceinline__ float bf2f(unsigned short h) {
    union { unsigned int u; float f; } v; v.u = ((unsigned int)h) << 16;
    return v.f;
}

static __device__ __forceinline__ void gload_lds16(const void* g, void* l) {
    __builtin_amdgcn_global_load_lds((const __attribute__((address_space(1))) void*)g,
                                     (__attribute__((address_space(3))) void*)l,
                                     16, 0, 0);
}

// ---------------------------------------------------------------------------
// K0: fp32 -> bf16 conversion of x, [w_proj;w_g] (concat as 4096x1024), w_o
// ---------------------------------------------------------------------------
__global__ __launch_bounds__(256) void convert_kernel(
    const float* __restrict__ x, const float* __restrict__ wp,
    const float* __restrict__ wg, const float* __restrict__ wo,
    unsigned short* __restrict__ xb, unsigned short* __restrict__ wcat,
    unsigned short* __restrict__ wob)
{
    const int NX  = (LSEQ * EMB) / 4;
    const int NWP = (3 * EMB * EMB) / 4;
    const int NWG = (EMB * EMB) / 4;
    const int NWO = (EMB * EMB) / 4;
    const int total = NX + NWP + NWG + NWO;
    for (int i = blockIdx.x * blockDim.x + threadIdx.x; i < total;
         i += gridDim.x * blockDim.x) {
        const float4* src; unsigned short* dst; int j;
        if (i < NX)                  { src = (const float4*)x;  dst = xb;                  j = i; }
        else if (i < NX + NWP)       { src = (const float4*)wp; dst = wcat;                j = i - NX; }
        else if (i < NX + NWP + NWG) { src = (const float4*)wg; dst = wcat + 3 * EMB * EMB; j = i - NX - NWP; }
        else                         { src = (const float4*)wo; dst = wob;                 j = i - NX - NWP - NWG; }
        float4 v = src[j];
        u16x4 o;
        o.x = f2bf(v.x); o.y = f2bf(v.y); o.z = f2bf(v.z); o.w = f2bf(v.w);
        *(u16x4*)(dst + (size_t)j * 4) = o;
    }
}

// ---------------------------------------------------------------------------
// Mask decode (bool 1B / int32 / f32 tolerant) -> additive f32 mask bias
// ---------------------------------------------------------------------------
__global__ void decode_mask_kernel(const unsigned char* __restrict__ mask,
                                   float* __restrict__ mbias)
{
    __shared__ int cnt;
    if (threadIdx.x == 0) cnt = 0;
    __syncthreads();
    int c = 0;
    for (int i = threadIdx.x; i < LSEQ; i += 256) c += (mask[i] != 0);
    atomicAdd(&cnt, c);
    __syncthreads();
    bool isbyte = cnt > LSEQ / 2;
    for (int k = threadIdx.x; k < LSEQ; k += 256) {
        bool v;
        if (isbyte) v = (mask[k] != 0);
        else        v = ((mask[4*k] | mask[4*k+1] | mask[4*k+2] | mask[4*k+3]) != 0);
        mbias[k] = v ? 0.f : -1e30f;
    }
}

// ---------------------------------------------------------------------------
// GEMM: C[M,N] = A[M,K] * B[N,K]^T  (m97-style 128x128, BK=64)
// ---------------------------------------------------------------------------
#define BM 128
#define BN 128
#define BK 64

__global__ __launch_bounds__(256) void gemm_bt_kernel(
    const unsigned short* __restrict__ A, const unsigned short* __restrict__ B,
    void* __restrict__ Cout, const float* __restrict__ biasN,
    int M, int N, int K, int epi)
{
    __shared__ unsigned short As[BM][BK];
    __shared__ unsigned short Bs[BN][BK];
    const int tid  = threadIdx.x;
    const int lane = tid & 63;
    const int w    = tid >> 6;
    const int wr   = w >> 1, wc = w & 1;
    const int row0 = blockIdx.y * BM;
    const int col0 = blockIdx.x * BN;
    const int lr = lane & 15;
    const int lg = lane >> 4;

    f32x4 acc[4][4];
    const f32x4 zf = {0.f, 0.f, 0.f, 0.f};
#pragma unroll
    for (int m = 0; m < 4; ++m)
#pragma unroll
        for (int n = 0; n < 4; ++n) acc[m][n] = zf;

    const char* Ab = (const char*)(A + (size_t)row0 * K);
    const char* Bb = (const char*)(B + (size_t)col0 * K);
    const int Kb = K * 2;

    for (int kt = 0; kt < K; kt += BK) {
#pragma unroll
        for (int i = 0; i < 4; ++i) {
            int o = (i * 256 + tid) * 16;
            int r = o >> 7, cb = o & 127;
            gload_lds16(Ab + (size_t)r * Kb + kt * 2 + cb, (char*)As + o);
        }
#pragma unroll
        for (int i = 0; i < 4; ++i) {
            int o = (i * 256 + tid) * 16;
            int r = o >> 7, cb = o & 127;
            gload_lds16(Bb + (size_t)r * Kb + kt * 2 + cb, (char*)Bs + o);
        }
        __syncthreads();
#pragma unroll
        for (int kk = 0; kk < 2; ++kk) {
            bf16x8 af[4], bfr[4];
            const int lk = kk * 32 + lg * 8;
#pragma unroll
            for (int m = 0; m < 4; ++m) af[m]  = *(const bf16x8*)&As[wr * 64 + m * 16 + lr][lk];
#pragma unroll
            for (int n = 0; n < 4; ++n) bfr[n] = *(const bf16x8*)&Bs[wc * 64 + n * 16 + lr][lk];
#pragma unroll
            for (int m = 0; m < 4; ++m)
#pragma unroll
                for (int n = 0; n < 4; ++n)
                    acc[m][n] = __builtin_amdgcn_mfma_f32_16x16x32_bf16(af[m], bfr[n], acc[m][n], 0, 0, 0);
        }
        __syncthreads();
    }

#pragma unroll
    for (int m = 0; m < 4; ++m)
#pragma unroll
        for (int n = 0; n < 4; ++n) {
            const int col = col0 + wc * 64 + n * 16 + lr;
#pragma unroll
            for (int r = 0; r < 4; ++r) {
                const int row = row0 + wr * 64 + m * 16 + lg * 4 + r;
                if (epi == 0)
                    ((unsigned short*)Cout)[(size_t)row * N + col] = f2bf(acc[m][n][r]);
                else
                    ((float*)Cout)[(size_t)row * N + col] = acc[m][n][r] + biasN[col];
            }
        }
}

// ---------------------------------------------------------------------------
// K2a: rearrange proj output T[L,4096]: Q (pre-scaled by 1/8) / K -> [h][l][64];
// gate -> sigmoid
// ---------------------------------------------------------------------------
__global__ __launch_bounds__(256) void rearrange_kernel(
    const unsigned short* __restrict__ T, const float* __restrict__ bg,
    unsigned short* __restrict__ Qh, unsigned short* __restrict__ Kh,
    unsigned short* __restrict__ G)
{
    const int l = blockIdx.x;
    const int t = threadIdx.x;
    const unsigned short* trow = T + (size_t)l * 4096;
    {
        const int tt = t & 127;
        const int h  = tt >> 3;
        const int c0 = (tt & 7) * 8;
        const bool isq = (t < 128);
        const int srcoff = h * 192 + (isq ? 0 : 64) + c0;
        u16x8 v = *(const u16x8*)(trow + srcoff);
        if (isq) {
#pragma unroll
            for (int j = 0; j < 8; ++j) v[j] = f2bf(bf2f(v[j]) * SCALEF);
        }
        unsigned short* dst = (isq ? Qh : Kh) + ((size_t)h * LSEQ + l) * HWID + c0;
        *(u16x8*)dst = v;
    }
    {
        const int f0 = t * 4;
        float4 b4 = *(const float4*)(bg + f0);
        u16x4 tv = *(const u16x4*)(trow + 3 * EMB + f0);
        u16x4 o;
        o.x = f2bf(1.f / (1.f + __expf(-(bf2f(tv.x) + b4.x))));
        o.y = f2bf(1.f / (1.f + __expf(-(bf2f(tv.y) + b4.y))));
        o.z = f2bf(1.f / (1.f + __expf(-(bf2f(tv.z) + b4.z))));
        o.w = f2bf(1.f / (1.f + __expf(-(bf2f(tv.w) + b4.w))));
        *(u16x4*)(G + (size_t)l * EMB + f0) = o;
    }
}

// ---------------------------------------------------------------------------
// K2b: V transpose -> VT[h][c][l] via 64x64 LDS tiles
// ---------------------------------------------------------------------------
__global__ __launch_bounds__(256) void vtrans_kernel(
    const unsigned short* __restrict__ T, unsigned short* __restrict__ VT)
{
    __shared__ unsigned short tile[64][72];
    const int h  = blockIdx.x & 15;
    const int lt = blockIdx.x >> 4;
    const int l0 = lt * 64;
    const int t  = threadIdx.x;
    {
        const int i = t >> 2, c0 = (t & 3) * 16;
        const unsigned short* src = T + (size_t)(l0 + i) * 4096 + h * 192 + 128;
        *(u16x8*)&tile[i][c0]     = *(const u16x8*)(src + c0);
        *(u16x8*)&tile[i][c0 + 8] = *(const u16x8*)(src + c0 + 8);
    }
    __syncthreads();
    {
        const int c = t >> 2, j0 = (t & 3) * 16;
        unsigned short* dst = VT + ((size_t)h * HWID + c) * LSEQ + l0 + j0;
        u16x8 a, b;
#pragma unroll
        for (int j = 0; j < 8; ++j) a[j] = tile[j0 + j][c];
#pragma unroll
        for (int j = 0; j < 8; ++j) b[j] = tile[j0 + 8 + j][c];
        *(u16x8*)dst       = a;
        *(u16x8*)(dst + 8) = b;
    }
}

// ---------------------------------------------------------------------------
// K3: fused attention v12 — ALL-16-HEADS blocks: every 64B bias line is
// consumed entirely inside one block (thread loads a full line = 4xb128),
// so FETCH == 268MB by construction; no XCD choreography needed.
// Grid 512 = 128 q-tiles x split-k 4 (512 keys/split, NT=16 bodies of 32).
// Block 512 = 8 waves; wave w handles heads {w, w+8} sequentially over the
// same 16 q-rows. Bias LDS = 16 head-planes [16q][stride36] f32 (reads and
// writes both exactly 2-way = free). Per body, issue order (asm-pinned):
//   K0,V0,K1 -> bias(t+1) -> head0 -> V1 -> head1 -> barrier ->
//   writeBias -> lgkm0 -> barrier
// Compiler-counted waits keep bias in flight ~a full body; no manual vmcnt.
// LDS 59.4 KB, VGPR target <=128 -> 2 blocks/CU (16 waves).
// ---------------------------------------------------------------------------
#define SPLITS 4
#define NT 16          // bodies per split: 512 / KT=32

__global__ __launch_bounds__(512, 4) void attn_kernel(
    const unsigned short* __restrict__ Qh, const unsigned short* __restrict__ Kh,
    const unsigned short* __restrict__ VT, const float* __restrict__ bias,
    const float* __restrict__ mbias,
    float* __restrict__ Op, float* __restrict__ Ml)
{
    __shared__ float bias_s[16 * 576];           // 36.9 KB: 16 head-planes [16q][36]
    __shared__ unsigned short ps[8][2][16][40];  // 20.5 KB per-wave/per-head P buffers
    __shared__ float mk[512];                    // 2 KB additive mask (this split)

    const int tid  = threadIdx.x;
    const int lane = tid & 63;
    const int w    = tid >> 6;
    const int qsub = blockIdx.x >> 2;
    const int sp   = blockIdx.x & 3;
    const int h0   = w;
    const int h1   = w + 8;
    const int q0   = qsub * 16;
    const int koff = sp * 512;
    const int lr   = lane & 15;
    const int lg   = lane >> 4;

    // Q fragments for both heads (registers for the whole kernel)
    const unsigned short* Q0 = Qh + ((size_t)h0 * LSEQ + q0) * HWID;
    const unsigned short* Q1 = Qh + ((size_t)h1 * LSEQ + q0) * HWID;
    const bf16x8 qa00 = *(const bf16x8*)(Q0 + lr * HWID + lg * 8);
    const bf16x8 qa01 = *(const bf16x8*)(Q0 + lr * HWID + 32 + lg * 8);
    const bf16x8 qa10 = *(const bf16x8*)(Q1 + lr * HWID + lg * 8);
    const bf16x8 qa11 = *(const bf16x8*)(Q1 + lr * HWID + 32 + lg * 8);

    const unsigned short* Kb0 = Kh + ((size_t)h0 * LSEQ + koff) * HWID;
    const unsigned short* Kb1 = Kh + ((size_t)h1 * LSEQ + koff) * HWID;
    const unsigned short* Vb0 = VT + (size_t)h0 * HWID * LSEQ + koff;
    const unsigned short* Vb1 = VT + (size_t)h1 * HWID * LSEQ + koff;
    const float* bias_base = bias;

    const int bq = tid >> 5;        // 0..15 (q-row this thread stages)
    const int bk = tid & 31;        // 0..31 (key this thread stages)
    const int bidx = bq * 36 + bk;  // plane-local LDS index

    // one full 64B line (16 heads) per thread
    auto loadBias = [&](int t, float4* bv) {
        const float* src = bias_base +
            ((size_t)(q0 + bq) * LSEQ + (koff + t * 32 + bk)) * NH;
#pragma unroll
        for (int i = 0; i < 4; ++i) bv[i] = *(const float4*)(src + i * 4);
    };
    // line -> 16 head-planes (stride-36: write 2-way, read 2-way = free)
    auto writeBias = [&](const float4* bv) {
#pragma unroll
        for (int hh = 0; hh < 4; ++hh) {
            bias_s[(hh * 4 + 0) * 576 + bidx] = bv[hh].x;
            bias_s[(hh * 4 + 1) * 576 + bidx] = bv[hh].y;
            bias_s[(hh * 4 + 2) * 576 + bidx] = bv[hh].z;
            bias_s[(hh * 4 + 3) * 576 + bidx] = bv[hh].w;
        }
    };
    auto loadK = [&](const unsigned short* Kb, int kgl, bf16x8 (&kb)[2][2]) {
#pragma unroll
        for (int t2 = 0; t2 < 2; ++t2) {
            const unsigned short* kp = Kb + (size_t)(kgl + t2 * 16 + lr) * HWID + lg * 8;
            kb[t2][0] = *(const bf16x8*)kp;
            kb[t2][1] = *(const bf16x8*)(kp + 32);
        }
    };
    auto loadV = [&](const unsigned short* Vb, int kgl, bf16x8 (&vb)[4]) {
#pragma unroll
        for (int ct = 0; ct < 4; ++ct)
            vb[ct] = *(const bf16x8*)(Vb + (size_t)(ct * 16 + lr) * LSEQ + kgl + lg * 8);
    };

    bf16x8 ones;
#pragma unroll
    for (int j2 = 0; j2 < 8; ++j2) ones[j2] = (short)0x3F80;  // bf16 1.0

    const f32x4 zf = {0.f, 0.f, 0.f, 0.f};
    float mrowA[4], mrowB[4];
    f32x4 accA[4], accB[4], lsumA, lsumB;
#pragma unroll
    for (int r = 0; r < 4; ++r) { mrowA[r] = -1e30f; mrowB[r] = -1e30f; }
#pragma unroll
    for (int c = 0; c < 4; ++c) { accA[c] = zf; accB[c] = zf; }
    lsumA = zf; lsumB = zf;

    auto computeHead = [&](const bf16x8 (&kb)[2][2], const bf16x8 (&vb)[4],
                           const bf16x8 &qaA, const bf16x8 &qaB,
                           const float* bpl, int kgl,
                           float (&mrow)[4], f32x4 (&acc)[4], f32x4 &lsum,
                           unsigned short (*psb)[40]) {
        f32x4 S[2];
#pragma unroll
        for (int t2 = 0; t2 < 2; ++t2) {
            f32x4 s = zf;
            s = __builtin_amdgcn_mfma_f32_16x16x32_bf16(qaA, kb[t2][0], s, 0, 0, 0);
            s = __builtin_amdgcn_mfma_f32_16x16x32_bf16(qaB, kb[t2][1], s, 0, 0, 0);
            S[t2] = s;
        }
        const float m0 = mk[kgl + lr];
        const float m1 = mk[kgl + 16 + lr];
        float sc0[4], sc1[4], lm[4];
#pragma unroll
        for (int r = 0; r < 4; ++r) {
            const int qrow = (lg * 4 + r) * 36;
            sc0[r] = S[0][r] + bpl[qrow + lr] + m0;
            sc1[r] = S[1][r] + bpl[qrow + 16 + lr] + m1;
            lm[r] = fmaxf(sc0[r], sc1[r]);
        }
        const float need = fmaxf(fmaxf(lm[0] - mrow[0], lm[1] - mrow[1]),
                                 fmaxf(lm[2] - mrow[2], lm[3] - mrow[3]));
        if (!__all(need <= 8.0f)) {
            float rm[4];
#pragma unroll
            for (int r = 0; r < 4; ++r) rm[r] = lm[r];
#pragma unroll
            for (int off = 1; off < 16; off <<= 1)
#pragma unroll
                for (int r = 0; r < 4; ++r)
                    rm[r] = fmaxf(rm[r], __shfl_xor(rm[r], off, 64));
            float sf[4];
#pragma unroll
            for (int r = 0; r < 4; ++r) {
                const float mn = fmaxf(mrow[r], rm[r]);
                sf[r] = __expf(mrow[r] - mn);
                mrow[r] = mn;
            }
#pragma unroll
            for (int ct = 0; ct < 4; ++ct)
#pragma unroll
                for (int r = 0; r < 4; ++r) acc[ct][r] *= sf[r];
#pragma unroll
            for (int r = 0; r < 4; ++r) lsum[r] *= sf[r];
        }
        float p0[4], p1[4];
#pragma unroll
        for (int r = 0; r < 4; ++r) {
            p0[r] = __expf(sc0[r] - mrow[r]);   // masked: exp(-huge) = 0
            p1[r] = __expf(sc1[r] - mrow[r]);
        }
#pragma unroll
        for (int r = 0; r < 4; ++r) {
            psb[lg * 4 + r][lr]      = f2bf(p0[r]);
            psb[lg * 4 + r][16 + lr] = f2bf(p1[r]);
        }
        const bf16x8 pa = *(const bf16x8*)&psb[lr][lg * 8];
#pragma unroll
        for (int ct = 0; ct < 4; ++ct)
            acc[ct] = __builtin_amdgcn_mfma_f32_16x16x32_bf16(pa, vb[ct], acc[ct], 0, 0, 0);
        lsum = __builtin_amdgcn_mfma_f32_16x16x32_bf16(pa, ones, lsum, 0, 0, 0);
    };

    // ---- prologue ----
    float4 bv[4];
    loadBias(0, bv);
    mk[tid] = mbias[koff + tid];
    __syncthreads();            // drains bias(0) loads + mask store
    writeBias(bv);
    asm volatile("s_waitcnt lgkmcnt(0)" ::: "memory");
    __builtin_amdgcn_s_barrier();   // plane(0) visible

    const float* pl0 = bias_s + (size_t)h0 * 576;
    const float* pl1 = bias_s + (size_t)h1 * 576;

#pragma unroll 1
    for (int t = 0; t < NT; ++t) {
        const int kgl = t * 32;
        bf16x8 kbA[2][2], vbA[4], kbB[2][2], vbB[4];

        loadK(Kb0, kgl, kbA);
        loadV(Vb0, kgl, vbA);
        loadK(Kb1, kgl, kbB);
        asm volatile("" ::: "memory");
        if (t + 1 < NT) loadBias(t + 1, bv);   // youngest: never force-drained
        asm volatile("" ::: "memory");

        computeHead(kbA, vbA, qa00, qa01, pl0, kgl, mrowA, accA, lsumA, ps[w][0]);
        asm volatile("" ::: "memory");
        loadV(Vb1, kgl, vbB);
        asm volatile("" ::: "memory");
        computeHead(kbB, vbB, qa10, qa11, pl1, kgl, mrowB, accB, lsumB, ps[w][1]);

        asm volatile("" ::: "memory");
        __builtin_amdgcn_s_barrier();          // all waves done reading plane(t)
        if (t + 1 < NT) writeBias(bv);
        asm volatile("s_waitcnt lgkmcnt(0)" ::: "memory");
        __builtin_amdgcn_s_barrier();          // plane(t+1) visible
    }

    // store partials (unnormalized) for both heads
#pragma unroll
    for (int ct = 0; ct < 4; ++ct)
#pragma unroll
        for (int r = 0; r < 4; ++r) {
            const int q = q0 + lg * 4 + r;
            Op[(((size_t)sp * NH + h0) * LSEQ + q) * HWID + ct * 16 + lr] = accA[ct][r];
            Op[(((size_t)sp * NH + h1) * LSEQ + q) * HWID + ct * 16 + lr] = accB[ct][r];
        }
    if (lr == 0) {
#pragma unroll
        for (int r = 0; r < 4; ++r) {
            const int q = q0 + lg * 4 + r;
            const size_t r0 = ((size_t)sp * NH + h0) * LSEQ + q;
            const size_t r1 = ((size_t)sp * NH + h1) * LSEQ + q;
            Ml[r0 * 2 + 0] = mrowA[r];
            Ml[r0 * 2 + 1] = lsumA[r];
            Ml[r1 * 2 + 0] = mrowB[r];
            Ml[r1 * 2 + 1] = lsumB[r];
        }
    }
}

// ---------------------------------------------------------------------------
// K3b: combine 4 split-k partials, normalize, apply gate -> bf16 Y
// ---------------------------------------------------------------------------
__global__ __launch_bounds__(256) void combine_kernel(
    const float* __restrict__ Op, const float* __restrict__ Ml,
    const unsigned short* __restrict__ G, unsigned short* __restrict__ Yb)
{
    const int t   = threadIdx.x;
    const int c   = t & 63;
    const int row = blockIdx.x * 4 + (t >> 6);      // [0, NH*LSEQ)
    const int h   = row >> 11;
    const int q   = row & (LSEQ - 1);

    size_t rs[SPLITS];
    float m[SPLITS], l[SPLITS];
    float mx = -1e30f;
#pragma unroll
    for (int s = 0; s < SPLITS; ++s) {
        rs[s] = ((size_t)s * NH + h) * LSEQ + q;
        m[s] = Ml[rs[s] * 2 + 0];
        l[s] = Ml[rs[s] * 2 + 1];
        mx = fmaxf(mx, m[s]);
    }
    float den = 0.f, y = 0.f;
#pragma unroll
    for (int s = 0; s < SPLITS; ++s) {
        const float a = __expf(m[s] - mx);
        den += l[s] * a;
        y   += Op[rs[s] * HWID + c] * a;
    }
    y /= den;
    const int e = h * HWID + c;
    const float g = bf2f(G[(size_t)q * EMB + e]);
    Yb[(size_t)q * EMB + e] = f2bf(y * g);
}

// ---------------------------------------------------------------------------
extern "C" void kernel_launch(void* const* d_in, const int* in_sizes, int n_in,
                              void* d_out, int out_size, void* d_ws, size_t ws_size,
                              hipStream_t stream) {
    const float*         x      = (const float*)d_in[0];
    const unsigned char* mask   = (const unsigned char*)d_in[1];
    const float*         bias   = (const float*)d_in[2];
    const float*         w_proj = (const float*)d_in[3];
    const float*         w_o    = (const float*)d_in[4];
    const float*         b_o    = (const float*)d_in[5];
    const float*         w_g    = (const float*)d_in[6];
    const float*         b_g    = (const float*)d_in[7];
    float* out = (float*)d_out;
    (void)in_sizes; (void)n_in; (void)out_size; (void)ws_size;

    char* p = (char*)d_ws;
    auto alloc = [&](size_t bytes) {
        char* r = p; p += (bytes + 255) & ~(size_t)255; return r;
    };
    unsigned short* xb    = (unsigned short*)alloc((size_t)LSEQ * EMB * 2);
    unsigned short* wcat  = (unsigned short*)alloc((size_t)4 * EMB * EMB * 2);
    unsigned short* wob   = (unsigned short*)alloc((size_t)EMB * EMB * 2);
    unsigned short* T     = (unsigned short*)alloc((size_t)LSEQ * 4096 * 2);
    unsigned short* Qh    = (unsigned short*)alloc((size_t)NH * LSEQ * HWID * 2);
    unsigned short* Kh    = (unsigned short*)alloc((size_t)NH * LSEQ * HWID * 2);
    unsigned short* VT    = (unsigned short*)alloc((size_t)NH * HWID * LSEQ * 2);
    unsigned short* G     = (unsigned short*)alloc((size_t)LSEQ * EMB * 2);
    unsigned short* Yb    = (unsigned short*)alloc((size_t)LSEQ * EMB * 2);
    float*          mb    = (float*)alloc((size_t)LSEQ * 4);
    float*          Op    = (float*)alloc((size_t)SPLITS * NH * LSEQ * HWID * 4);
    float*          Ml    = (float*)alloc((size_t)SPLITS * NH * LSEQ * 2 * 4);

    convert_kernel<<<1024, 256, 0, stream>>>(x, w_proj, w_g, w_o, xb, wcat, wob);
    decode_mask_kernel<<<1, 256, 0, stream>>>(mask, mb);
    gemm_bt_kernel<<<dim3(4096 / BN, LSEQ / BM), 256, 0, stream>>>(
        xb, wcat, (void*)T, nullptr, LSEQ, 4096, EMB, 0);
    rearrange_kernel<<<LSEQ, 256, 0, stream>>>(T, b_g, Qh, Kh, G);
    vtrans_kernel<<<NH * (LSEQ / 64), 256, 0, stream>>>(T, VT);
    attn_kernel<<<512, 512, 0, stream>>>(Qh, Kh, VT, bias, mb, Op, Ml);
    combine_kernel<<<NH * LSEQ / 4, 256, 0, stream>>>(Op, Ml, G, Yb);
    gemm_bt_kernel<<<dim3(EMB / BN, LSEQ / BM), 256, 0, stream>>>(
        Yb, wob, (void*)out, b_o, LSEQ, EMB, EMB, 1);
}

// Round 13
// 237.986 us; speedup vs baseline: 1.5907x; 1.5907x over previous
//
#include <hip/hip_runtime.h>
#include <stdint.h>

// Problem constants
#define LSEQ 2048
#define EMB  1024
#define NH   16
#define HWID 64
#define SCALEF 0.125f   // 1/sqrt(64), folded into Q during rearrange

typedef __attribute__((ext_vector_type(4))) float  f32x4;
typedef __attribute__((ext_vector_type(8))) short  bf16x8;   // 8 bf16 in 4 VGPRs (MFMA operand)
typedef __attribute__((ext_vector_type(8))) unsigned short u16x8;
typedef __attribute__((ext_vector_type(4))) unsigned short u16x4;

static __device__ __forceinline__ unsigned short f2bf(float f) {
    union { float f; unsigned int u; } v; v.f = f;
    unsigned int r = (v.u + 0x7FFFu + ((v.u >> 16) & 1u)) >> 16;  // RNE
    return (unsigned short)r;
}
static __device__ __forceinline__ float bf2f(unsigned short h) {
    union { unsigned int u; float f; } v; v.u = ((unsigned int)h) << 16;
    return v.f;
}

static __device__ __forceinline__ void gload_lds16(const void* g, void* l) {
    __builtin_amdgcn_global_load_lds((const __attribute__((address_space(1))) void*)g,
                                     (__attribute__((address_space(3))) void*)l,
                                     16, 0, 0);
}

// ---------------------------------------------------------------------------
// K0: fp32 -> bf16 conversion of x, [w_proj;w_g] (concat as 4096x1024), w_o
// ---------------------------------------------------------------------------
__global__ __launch_bounds__(256) void convert_kernel(
    const float* __restrict__ x, const float* __restrict__ wp,
    const float* __restrict__ wg, const float* __restrict__ wo,
    unsigned short* __restrict__ xb, unsigned short* __restrict__ wcat,
    unsigned short* __restrict__ wob)
{
    const int NX  = (LSEQ * EMB) / 4;
    const int NWP = (3 * EMB * EMB) / 4;
    const int NWG = (EMB * EMB) / 4;
    const int NWO = (EMB * EMB) / 4;
    const int total = NX + NWP + NWG + NWO;
    for (int i = blockIdx.x * blockDim.x + threadIdx.x; i < total;
         i += gridDim.x * blockDim.x) {
        const float4* src; unsigned short* dst; int j;
        if (i < NX)                  { src = (const float4*)x;  dst = xb;                  j = i; }
        else if (i < NX + NWP)       { src = (const float4*)wp; dst = wcat;                j = i - NX; }
        else if (i < NX + NWP + NWG) { src = (const float4*)wg; dst = wcat + 3 * EMB * EMB; j = i - NX - NWP; }
        else                         { src = (const float4*)wo; dst = wob;                 j = i - NX - NWP - NWG; }
        float4 v = src[j];
        u16x4 o;
        o.x = f2bf(v.x); o.y = f2bf(v.y); o.z = f2bf(v.z); o.w = f2bf(v.w);
        *(u16x4*)(dst + (size_t)j * 4) = o;
    }
}

// ---------------------------------------------------------------------------
// Mask decode (bool 1B / int32 / f32 tolerant) -> additive f32 mask bias
// ---------------------------------------------------------------------------
__global__ void decode_mask_kernel(const unsigned char* __restrict__ mask,
                                   float* __restrict__ mbias)
{
    __shared__ int cnt;
    if (threadIdx.x == 0) cnt = 0;
    __syncthreads();
    int c = 0;
    for (int i = threadIdx.x; i < LSEQ; i += 256) c += (mask[i] != 0);
    atomicAdd(&cnt, c);
    __syncthreads();
    bool isbyte = cnt > LSEQ / 2;
    for (int k = threadIdx.x; k < LSEQ; k += 256) {
        bool v;
        if (isbyte) v = (mask[k] != 0);
        else        v = ((mask[4*k] | mask[4*k+1] | mask[4*k+2] | mask[4*k+3]) != 0);
        mbias[k] = v ? 0.f : -1e30f;
    }
}

// ---------------------------------------------------------------------------
// GEMM: C[M,N] = A[M,K] * B[N,K]^T  (m97-style 128x128, BK=64)
// ---------------------------------------------------------------------------
#define BM 128
#define BN 128
#define BK 64

__global__ __launch_bounds__(256) void gemm_bt_kernel(
    const unsigned short* __restrict__ A, const unsigned short* __restrict__ B,
    void* __restrict__ Cout, const float* __restrict__ biasN,
    int M, int N, int K, int epi)
{
    __shared__ unsigned short As[BM][BK];
    __shared__ unsigned short Bs[BN][BK];
    const int tid  = threadIdx.x;
    const int lane = tid & 63;
    const int w    = tid >> 6;
    const int wr   = w >> 1, wc = w & 1;
    const int row0 = blockIdx.y * BM;
    const int col0 = blockIdx.x * BN;
    const int lr = lane & 15;
    const int lg = lane >> 4;

    f32x4 acc[4][4];
    const f32x4 zf = {0.f, 0.f, 0.f, 0.f};
#pragma unroll
    for (int m = 0; m < 4; ++m)
#pragma unroll
        for (int n = 0; n < 4; ++n) acc[m][n] = zf;

    const char* Ab = (const char*)(A + (size_t)row0 * K);
    const char* Bb = (const char*)(B + (size_t)col0 * K);
    const int Kb = K * 2;

    for (int kt = 0; kt < K; kt += BK) {
#pragma unroll
        for (int i = 0; i < 4; ++i) {
            int o = (i * 256 + tid) * 16;
            int r = o >> 7, cb = o & 127;
            gload_lds16(Ab + (size_t)r * Kb + kt * 2 + cb, (char*)As + o);
        }
#pragma unroll
        for (int i = 0; i < 4; ++i) {
            int o = (i * 256 + tid) * 16;
            int r = o >> 7, cb = o & 127;
            gload_lds16(Bb + (size_t)r * Kb + kt * 2 + cb, (char*)Bs + o);
        }
        __syncthreads();
#pragma unroll
        for (int kk = 0; kk < 2; ++kk) {
            bf16x8 af[4], bfr[4];
            const int lk = kk * 32 + lg * 8;
#pragma unroll
            for (int m = 0; m < 4; ++m) af[m]  = *(const bf16x8*)&As[wr * 64 + m * 16 + lr][lk];
#pragma unroll
            for (int n = 0; n < 4; ++n) bfr[n] = *(const bf16x8*)&Bs[wc * 64 + n * 16 + lr][lk];
#pragma unroll
            for (int m = 0; m < 4; ++m)
#pragma unroll
                for (int n = 0; n < 4; ++n)
                    acc[m][n] = __builtin_amdgcn_mfma_f32_16x16x32_bf16(af[m], bfr[n], acc[m][n], 0, 0, 0);
        }
        __syncthreads();
    }

#pragma unroll
    for (int m = 0; m < 4; ++m)
#pragma unroll
        for (int n = 0; n < 4; ++n) {
            const int col = col0 + wc * 64 + n * 16 + lr;
#pragma unroll
            for (int r = 0; r < 4; ++r) {
                const int row = row0 + wr * 64 + m * 16 + lg * 4 + r;
                if (epi == 0)
                    ((unsigned short*)Cout)[(size_t)row * N + col] = f2bf(acc[m][n][r]);
                else
                    ((float*)Cout)[(size_t)row * N + col] = acc[m][n][r] + biasN[col];
            }
        }
}

// ---------------------------------------------------------------------------
// K2a: rearrange proj output T[L,4096]: Q (pre-scaled by 1/8) / K -> [h][l][64];
// gate -> sigmoid
// ---------------------------------------------------------------------------
__global__ __launch_bounds__(256) void rearrange_kernel(
    const unsigned short* __restrict__ T, const float* __restrict__ bg,
    unsigned short* __restrict__ Qh, unsigned short* __restrict__ Kh,
    unsigned short* __restrict__ G)
{
    const int l = blockIdx.x;
    const int t = threadIdx.x;
    const unsigned short* trow = T + (size_t)l * 4096;
    {
        const int tt = t & 127;
        const int h  = tt >> 3;
        const int c0 = (tt & 7) * 8;
        const bool isq = (t < 128);
        const int srcoff = h * 192 + (isq ? 0 : 64) + c0;
        u16x8 v = *(const u16x8*)(trow + srcoff);
        if (isq) {
#pragma unroll
            for (int j = 0; j < 8; ++j) v[j] = f2bf(bf2f(v[j]) * SCALEF);
        }
        unsigned short* dst = (isq ? Qh : Kh) + ((size_t)h * LSEQ + l) * HWID + c0;
        *(u16x8*)dst = v;
    }
    {
        const int f0 = t * 4;
        float4 b4 = *(const float4*)(bg + f0);
        u16x4 tv = *(const u16x4*)(trow + 3 * EMB + f0);
        u16x4 o;
        o.x = f2bf(1.f / (1.f + __expf(-(bf2f(tv.x) + b4.x))));
        o.y = f2bf(1.f / (1.f + __expf(-(bf2f(tv.y) + b4.y))));
        o.z = f2bf(1.f / (1.f + __expf(-(bf2f(tv.z) + b4.z))));
        o.w = f2bf(1.f / (1.f + __expf(-(bf2f(tv.w) + b4.w))));
        *(u16x4*)(G + (size_t)l * EMB + f0) = o;
    }
}

// ---------------------------------------------------------------------------
// K2b: V transpose -> VT[h][c][l] via 64x64 LDS tiles
// ---------------------------------------------------------------------------
__global__ __launch_bounds__(256) void vtrans_kernel(
    const unsigned short* __restrict__ T, unsigned short* __restrict__ VT)
{
    __shared__ unsigned short tile[64][72];
    const int h  = blockIdx.x & 15;
    const int lt = blockIdx.x >> 4;
    const int l0 = lt * 64;
    const int t  = threadIdx.x;
    {
        const int i = t >> 2, c0 = (t & 3) * 16;
        const unsigned short* src = T + (size_t)(l0 + i) * 4096 + h * 192 + 128;
        *(u16x8*)&tile[i][c0]     = *(const u16x8*)(src + c0);
        *(u16x8*)&tile[i][c0 + 8] = *(const u16x8*)(src + c0 + 8);
    }
    __syncthreads();
    {
        const int c = t >> 2, j0 = (t & 3) * 16;
        unsigned short* dst = VT + ((size_t)h * HWID + c) * LSEQ + l0 + j0;
        u16x8 a, b;
#pragma unroll
        for (int j = 0; j < 8; ++j) a[j] = tile[j0 + j][c];
#pragma unroll
        for (int j = 0; j < 8; ++j) b[j] = tile[j0 + 8 + j][c];
        *(u16x8*)dst       = a;
        *(u16x8*)(dst + 8) = b;
    }
}

// ---------------------------------------------------------------------------
// K3: fused attention v13 — all-16-heads block, one head per wave.
// Block 1024 thr = 16 waves; wave w = head w over the block's 16 q-rows.
// Grid 256 = 128 q-tiles x split-2 -> exactly 1 block/CU. Every 64B bias
// line is consumed entirely INSIDE the block (thread pair loads a full
// line, 32B each, perfectly coalesced) -> FETCH == 268MB by construction,
// no cross-block reuse or XCD choreography needed.
// 2-slot bias ring (16 head-planes [16q][stride36] f32 per slot; writes and
// reads both exactly 2-way = free; 576%32==0 keeps half-pairs on one bank)
// -> ONE barrier per body. Per body issue order (asm-pinned):
//   V(t) -> K(t+1) [reg ping-pong] -> bias(t+1) [youngest]
// PV's compiler wait = vmcnt(6) (K+bias fly); the ds_write of bias(t+1) at
// body end is the only bias drain (~full-body flight) and also resolves
// K(t+1) before body t+1's QK -> QK never stalls. No manual vmcnt.
// VGPR ~110 (16-wave block enforces <=128 naturally; no min-waves hint).
// ---------------------------------------------------------------------------
#define NT 32          // bodies per split: 1024 / KT=32

__global__ __launch_bounds__(1024) void attn_kernel(
    const unsigned short* __restrict__ Qh, const unsigned short* __restrict__ Kh,
    const unsigned short* __restrict__ VT, const float* __restrict__ bias,
    const float* __restrict__ mbias,
    float* __restrict__ Op, float* __restrict__ Ml)
{
    __shared__ float bias_s[2][16][576];         // 73.7 KB: slot x head-plane [16q][36]
    __shared__ unsigned short ps[16][16][40];    // 20.5 KB per-wave P buffers
    __shared__ float mk[1024];                   // 4 KB additive mask (this split)

    const int tid  = threadIdx.x;
    const int lane = tid & 63;
    const int w    = tid >> 6;          // wave = head
    const int qsub = blockIdx.x >> 1;
    const int sp   = blockIdx.x & 1;
    const int h    = w;
    const int q0   = qsub * 16;
    const int koff = sp * 1024;
    const int lr   = lane & 15;
    const int lg   = lane >> 4;

    // Q fragments (registers for the whole kernel)
    const unsigned short* Qbase = Qh + ((size_t)h * LSEQ + q0) * HWID;
    const bf16x8 qa0 = *(const bf16x8*)(Qbase + lr * HWID + lg * 8);
    const bf16x8 qa1 = *(const bf16x8*)(Qbase + lr * HWID + 32 + lg * 8);

    const unsigned short* Kbase = Kh + ((size_t)h * LSEQ + koff) * HWID;
    const unsigned short* Vbase = VT + (size_t)h * HWID * LSEQ + koff;

    // bias staging: thread pair covers one 64B line (16 heads) of (q,k)
    const int li   = tid >> 1;          // 0..511 line index
    const int bq   = li >> 5;           // 0..15
    const int bk   = li & 31;           // 0..31
    const int half = tid & 1;           // 0: heads 0-7, 1: heads 8-15
    const float* bsrc0 = bias +
        ((size_t)(q0 + bq) * LSEQ + (koff + bk)) * NH + half * 8;
    const int bidx = bq * 36 + bk;

    auto loadBias = [&](int t, float4* bv) {
        const float* src = bsrc0 + (size_t)t * 32 * NH;
        bv[0] = *(const float4*)(src);
        bv[1] = *(const float4*)(src + 4);
    };
    auto writeBias = [&](int slot, const float4* bv) {
#pragma unroll
        for (int j = 0; j < 4; ++j) {
            bias_s[slot][half * 8 + j][bidx]     = ((const float*)&bv[0])[j];
            bias_s[slot][half * 8 + 4 + j][bidx] = ((const float*)&bv[1])[j];
        }
    };
    auto loadK = [&](int t, bf16x8 (&kb)[2][2]) {
        const int kgl = t * 32;
#pragma unroll
        for (int t2 = 0; t2 < 2; ++t2) {
            const unsigned short* kp = Kbase + (size_t)(kgl + t2 * 16 + lr) * HWID + lg * 8;
            kb[t2][0] = *(const bf16x8*)kp;
            kb[t2][1] = *(const bf16x8*)(kp + 32);
        }
    };

    bf16x8 ones;
#pragma unroll
    for (int j2 = 0; j2 < 8; ++j2) ones[j2] = (short)0x3F80;  // bf16 1.0

    float mrow[4];
    f32x4 acc[4], lsum;
    const f32x4 zf = {0.f, 0.f, 0.f, 0.f};
#pragma unroll
    for (int r = 0; r < 4; ++r) mrow[r] = -1e30f;
#pragma unroll
    for (int c = 0; c < 4; ++c) acc[c] = zf;
    lsum = zf;

    // ---- prologue ----
    float4 bv[2];
    bf16x8 kbA[2][2], kbB[2][2];
    loadBias(0, bv);
    loadK(0, kbA);
    mk[tid] = mbias[koff + tid];
    __syncthreads();                 // drains bias(0)+K(0)+mask
    writeBias(0, bv);
    asm volatile("s_waitcnt lgkmcnt(0)" ::: "memory");
    __builtin_amdgcn_s_barrier();    // slot 0 visible

    const unsigned short (*psb)[40] = nullptr; (void)psb;

    auto body = [&](int t, bf16x8 (&kbCur)[2][2], bf16x8 (&kbNxt)[2][2]) {
        const int kgl = t * 32;

        // issue V(t) (oldest)
        bf16x8 vb[4];
#pragma unroll
        for (int ct = 0; ct < 4; ++ct)
            vb[ct] = *(const bf16x8*)(Vbase + (size_t)(ct * 16 + lr) * LSEQ + kgl + lg * 8);
        asm volatile("" ::: "memory");
        // issue K(t+1)
        if (t + 1 < NT) loadK(t + 1, kbNxt);
        asm volatile("" ::: "memory");
        // issue bias(t+1) (youngest; drained only at writeBias below)
        if (t + 1 < NT) loadBias(t + 1, bv);
        asm volatile("" ::: "memory");

        // QK^T with kbCur (resolved at end of previous body)
        f32x4 S[2];
#pragma unroll
        for (int t2 = 0; t2 < 2; ++t2) {
            f32x4 s = zf;
            s = __builtin_amdgcn_mfma_f32_16x16x32_bf16(qa0, kbCur[t2][0], s, 0, 0, 0);
            s = __builtin_amdgcn_mfma_f32_16x16x32_bf16(qa1, kbCur[t2][1], s, 0, 0, 0);
            S[t2] = s;
        }

        // softmax from this wave's head-plane + additive mask
        const float* bpl = &bias_s[t & 1][w][0];
        const float m0 = mk[kgl + lr];
        const float m1 = mk[kgl + 16 + lr];
        float sc0[4], sc1[4], lm[4];
#pragma unroll
        for (int r = 0; r < 4; ++r) {
            const int qrow = (lg * 4 + r) * 36;
            sc0[r] = S[0][r] + bpl[qrow + lr] + m0;
            sc1[r] = S[1][r] + bpl[qrow + 16 + lr] + m1;
            lm[r] = fmaxf(sc0[r], sc1[r]);
        }
        const float need = fmaxf(fmaxf(lm[0] - mrow[0], lm[1] - mrow[1]),
                                 fmaxf(lm[2] - mrow[2], lm[3] - mrow[3]));
        if (!__all(need <= 8.0f)) {
            float rm[4];
#pragma unroll
            for (int r = 0; r < 4; ++r) rm[r] = lm[r];
#pragma unroll
            for (int off = 1; off < 16; off <<= 1)
#pragma unroll
                for (int r = 0; r < 4; ++r)
                    rm[r] = fmaxf(rm[r], __shfl_xor(rm[r], off, 64));
            float sf[4];
#pragma unroll
            for (int r = 0; r < 4; ++r) {
                const float mn = fmaxf(mrow[r], rm[r]);
                sf[r] = __expf(mrow[r] - mn);
                mrow[r] = mn;
            }
#pragma unroll
            for (int ct = 0; ct < 4; ++ct)
#pragma unroll
                for (int r = 0; r < 4; ++r) acc[ct][r] *= sf[r];
#pragma unroll
            for (int r = 0; r < 4; ++r) lsum[r] *= sf[r];
        }

        float p0[4], p1[4];
#pragma unroll
        for (int r = 0; r < 4; ++r) {
            p0[r] = __expf(sc0[r] - mrow[r]);   // masked: exp(-huge) = 0
            p1[r] = __expf(sc1[r] - mrow[r]);
        }

        // P -> per-wave LDS (S-layout write, A-frag read)
#pragma unroll
        for (int r = 0; r < 4; ++r) {
            ps[w][lg * 4 + r][lr]      = f2bf(p0[r]);
            ps[w][lg * 4 + r][16 + lr] = f2bf(p1[r]);
        }
        const bf16x8 pa = *(const bf16x8*)&ps[w][lr][lg * 8];

        // PV + ones-MFMA (wait vmcnt(6): V done, K(t+1)+bias(t+1) fly)
#pragma unroll
        for (int ct = 0; ct < 4; ++ct)
            acc[ct] = __builtin_amdgcn_mfma_f32_16x16x32_bf16(pa, vb[ct], acc[ct], 0, 0, 0);
        lsum = __builtin_amdgcn_mfma_f32_16x16x32_bf16(pa, ones, lsum, 0, 0, 0);

        // write bias(t+1) to the other slot (this is the bias drain point;
        // it also resolves K(t+1) before the next body's QK)
        if (t + 1 < NT) writeBias((t + 1) & 1, bv);
        asm volatile("s_waitcnt lgkmcnt(0)" ::: "memory");
        __builtin_amdgcn_s_barrier();   // single barrier per body
    };

#pragma unroll 1
    for (int tt = 0; tt < NT; tt += 2) {
        body(tt,     kbA, kbB);
        body(tt + 1, kbB, kbA);
    }

    // store partials (unnormalized)
    const size_t rowb = ((size_t)sp * NH + h) * LSEQ;
#pragma unroll
    for (int ct = 0; ct < 4; ++ct)
#pragma unroll
        for (int r = 0; r < 4; ++r) {
            const int q = q0 + lg * 4 + r;
            Op[(rowb + q) * HWID + ct * 16 + lr] = acc[ct][r];
        }
    if (lr == 0) {
#pragma unroll
        for (int r = 0; r < 4; ++r) {
            const int q = q0 + lg * 4 + r;
            Ml[(rowb + q) * 2 + 0] = mrow[r];
            Ml[(rowb + q) * 2 + 1] = lsum[r];
        }
    }
}

// ---------------------------------------------------------------------------
// K3b: combine split-k partials, normalize, apply gate -> bf16 Y
// ---------------------------------------------------------------------------
__global__ __launch_bounds__(256) void combine_kernel(
    const float* __restrict__ Op, const float* __restrict__ Ml,
    const unsigned short* __restrict__ G, unsigned short* __restrict__ Yb)
{
    const int t   = threadIdx.x;
    const int c   = t & 63;
    const int row = blockIdx.x * 4 + (t >> 6);      // [0, NH*LSEQ)
    const int h   = row >> 11;
    const int q   = row & (LSEQ - 1);
    const size_t r0 = (size_t)h * LSEQ + q;
    const size_t r1 = ((size_t)NH + h) * LSEQ + q;
    const float m0 = Ml[r0 * 2 + 0], l0 = Ml[r0 * 2 + 1];
    const float m1 = Ml[r1 * 2 + 0], l1 = Ml[r1 * 2 + 1];
    const float mx = fmaxf(m0, m1);
    const float a0 = __expf(m0 - mx), a1 = __expf(m1 - mx);
    const float inv = 1.f / (l0 * a0 + l1 * a1);
    const float o0 = Op[r0 * HWID + c];
    const float o1 = Op[r1 * HWID + c];
    const float y = (o0 * a0 + o1 * a1) * inv;
    const int e = h * HWID + c;
    const float g = bf2f(G[(size_t)q * EMB + e]);
    Yb[(size_t)q * EMB + e] = f2bf(y * g);
}

// ---------------------------------------------------------------------------
extern "C" void kernel_launch(void* const* d_in, const int* in_sizes, int n_in,
                              void* d_out, int out_size, void* d_ws, size_t ws_size,
                              hipStream_t stream) {
    const float*         x      = (const float*)d_in[0];
    const unsigned char* mask   = (const unsigned char*)d_in[1];
    const float*         bias   = (const float*)d_in[2];
    const float*         w_proj = (const float*)d_in[3];
    const float*         w_o    = (const float*)d_in[4];
    const float*         b_o    = (const float*)d_in[5];
    const float*         w_g    = (const float*)d_in[6];
    const float*         b_g    = (const float*)d_in[7];
    float* out = (float*)d_out;
    (void)in_sizes; (void)n_in; (void)out_size; (void)ws_size;

    char* p = (char*)d_ws;
    auto alloc = [&](size_t bytes) {
        char* r = p; p += (bytes + 255) & ~(size_t)255; return r;
    };
    unsigned short* xb    = (unsigned short*)alloc((size_t)LSEQ * EMB * 2);
    unsigned short* wcat  = (unsigned short*)alloc((size_t)4 * EMB * EMB * 2);
    unsigned short* wob   = (unsigned short*)alloc((size_t)EMB * EMB * 2);
    unsigned short* T     = (unsigned short*)alloc((size_t)LSEQ * 4096 * 2);
    unsigned short* Qh    = (unsigned short*)alloc((size_t)NH * LSEQ * HWID * 2);
    unsigned short* Kh    = (unsigned short*)alloc((size_t)NH * LSEQ * HWID * 2);
    unsigned short* VT    = (unsigned short*)alloc((size_t)NH * HWID * LSEQ * 2);
    unsigned short* G     = (unsigned short*)alloc((size_t)LSEQ * EMB * 2);
    unsigned short* Yb    = (unsigned short*)alloc((size_t)LSEQ * EMB * 2);
    float*          mb    = (float*)alloc((size_t)LSEQ * 4);
    float*          Op    = (float*)alloc((size_t)2 * NH * LSEQ * HWID * 4);
    float*          Ml    = (float*)alloc((size_t)2 * NH * LSEQ * 2 * 4);

    convert_kernel<<<1024, 256, 0, stream>>>(x, w_proj, w_g, w_o, xb, wcat, wob);
    decode_mask_kernel<<<1, 256, 0, stream>>>(mask, mb);
    gemm_bt_kernel<<<dim3(4096 / BN, LSEQ / BM), 256, 0, stream>>>(
        xb, wcat, (void*)T, nullptr, LSEQ, 4096, EMB, 0);
    rearrange_kernel<<<LSEQ, 256, 0, stream>>>(T, b_g, Qh, Kh, G);
    vtrans_kernel<<<NH * (LSEQ / 64), 256, 0, stream>>>(T, VT);
    attn_kernel<<<256, 1024, 0, stream>>>(Qh, Kh, VT, bias, mb, Op, Ml);
    combine_kernel<<<NH * LSEQ / 4, 256, 0, stream>>>(Op, Ml, G, Yb);
    gemm_bt_kernel<<<dim3(EMB / BN, LSEQ / BM), 256, 0, stream>>>(
        Yb, wob, (void*)out, b_o, LSEQ, EMB, EMB, 1);
}